// Round 12
// baseline (139.764 us; speedup 1.0000x reference)
//
#include <hip/hip_runtime.h>
#include <hip/hip_bf16.h>

// GlobalPointer logits: x = inputs@W+b -> split q/k per head -> RoPE(q) ->
// logits[b,h,m,n] = <q[b,m,h,:], k[b,n,h,:]> with mask+causal, /8.
// B=8 S=512 DIM=768 H=24 D=64. Output [8][24][512][512] f32.
// GEMM1 in MX-fp8 (e4m3, scale=1.0), swapped-operand MFMA (R7 form).
// GEMM2 v5: 768 blocks x 256 thr, 256x256 quadrant; K-only LDS (32KB,
// 4 blocks/CU), Q fragments direct from global, REGULAR f32x4 stores
// (R11's nontemporal stores cost +48us: nt bypasses L2 write aggregation).

typedef __bf16 bf16_t;
typedef __attribute__((ext_vector_type(8))) __bf16 bf16x8;
typedef __attribute__((ext_vector_type(4))) float f32x4;
typedef __attribute__((ext_vector_type(8))) int i32x8;

#define NEG_INF 1000000000000.0f
#define K1_8TH  125000000000.0f   // NEG_INF/8

// ws layout (bytes)
#define WS_A8   0                  // inputs fp8 [4096][768]    : 3,145,728
#define WS_WT8  3145728            // W^T fp8 [3072][768]       : 2,359,296
#define WS_Q    5505024            // Q bf16 [8][24][512][64]   : 12,582,912
#define WS_K    18087936           // K bf16 [8][24][512][64]   : 12,582,912
#define WS_RC   30670848           // ropeC f32 [512][64]       : 131,072
#define WS_RS   30801920           // ropeS f32 [512][64]       : 131,072

__device__ __forceinline__ unsigned short f2bf_bits(float x) {
  union { float f; unsigned u; } v; v.f = x;
  unsigned r = v.u + 0x7FFFu + ((v.u >> 16) & 1u);
  return (unsigned short)(r >> 16);
}

__device__ __forceinline__ int pack4_fp8(float a, float b, float c, float d) {
  int w = __builtin_amdgcn_cvt_pk_fp8_f32(a, b, 0, false);
  w = __builtin_amdgcn_cvt_pk_fp8_f32(c, d, w, true);
  return w;
}

#define GLD16(g, l) __builtin_amdgcn_global_load_lds( \
    (const __attribute__((address_space(1))) void*)(g), \
    (__attribute__((address_space(3))) void*)(l), 16, 0, 0)

// ---------------- fused prep ----------------
__global__ void prep_kernel(const float4* __restrict__ in, int4* __restrict__ outA,
                            const float* __restrict__ W, char* __restrict__ Wt8,
                            float* __restrict__ ropeC, float* __restrict__ ropeS) {
  __shared__ float s[32][33];
  if (blockIdx.x < 768) {
    int g = blockIdx.x * 256 + threadIdx.x;
    float4 v0 = in[g * 4 + 0];
    float4 v1 = in[g * 4 + 1];
    float4 v2 = in[g * 4 + 2];
    float4 v3 = in[g * 4 + 3];
    int4 o;
    o.x = pack4_fp8(v0.x, v0.y, v0.z, v0.w);
    o.y = pack4_fp8(v1.x, v1.y, v1.z, v1.w);
    o.z = pack4_fp8(v2.x, v2.y, v2.z, v2.w);
    o.w = pack4_fp8(v3.x, v3.y, v3.z, v3.w);
    outA[g] = o;
  } else if (blockIdx.x < 3072) {
    int bid = blockIdx.x - 768;
    int n0 = (bid % 96) * 32, k0 = (bid / 96) * 32;
    int tx = threadIdx.x & 31, ty = threadIdx.x >> 5;
#pragma unroll
    for (int r = 0; r < 4; ++r) {
      int k = k0 + ty + r * 8;
      s[ty + r * 8][tx] = W[(size_t)k * 3072 + n0 + tx];
    }
    __syncthreads();
    int kx = threadIdx.x & 7, tn = threadIdx.x >> 3;
    int w = pack4_fp8(s[4 * kx + 0][tn], s[4 * kx + 1][tn],
                      s[4 * kx + 2][tn], s[4 * kx + 3][tn]);
    *(int*)(Wt8 + (size_t)(n0 + tn) * 768 + k0 + 4 * kx) = w;
  } else {
    int g = (blockIdx.x - 3072) * 256 + threadIdx.x;
    int sp = g >> 6, c = g & 63;
    float inv = exp2f((float)(c >> 1) * -0.4152410118609203f);
    float ang = (float)sp * inv;
    float sn, cs;
    sincosf(ang, &sn, &cs);
    ropeC[g] = cs;
    ropeS[g] = sn;
  }
}

// ---------------- GEMM1 (MX-fp8): X = A*Wt^T + b, RoPE(q), split ----------------
__global__ __launch_bounds__(256) void gemm1_kernel(
    const char* __restrict__ A8, const char* __restrict__ Bt8,
    const float* __restrict__ bias,
    const float* __restrict__ ropeC, const float* __restrict__ ropeS,
    unsigned short* __restrict__ Qo, unsigned short* __restrict__ Ko) {
  __shared__ __align__(16) char As[2][128 * 128];
  __shared__ __align__(16) char Bs[2][128 * 128];
  const int tid = threadIdx.x;
  const int lane = tid & 63;
  const int wv = tid >> 6;
  const int wr = (wv >> 1) * 64;
  const int wc = (wv & 1) * 64;

  const int bid = blockIdx.x;
  const int swz = (bid & 7) * 96 + (bid >> 3);
  const int h = swz % 24;
  const int m0 = (swz / 24) * 128;
  const int n0 = h * 128;

  f32x4 acc[4][4];
#pragma unroll
  for (int i = 0; i < 4; ++i)
#pragma unroll
    for (int j = 0; j < 4; ++j) acc[i][j] = (f32x4){0.f, 0.f, 0.f, 0.f};

  const char* pA[4];
  const char* pB[4];
#pragma unroll
  for (int i = 0; i < 4; ++i) {
    int c = 4 * wv + i;
    int row = c * 8 + (lane >> 3);
    int srcslot = (lane & 7) ^ (row & 7);
    pA[i] = A8 + (size_t)(m0 + row) * 768 + srcslot * 16;
    pB[i] = Bt8 + (size_t)(n0 + row) * 768 + srcslot * 16;
  }

#define STAGE1(buf, k0) do { \
    _Pragma("unroll") \
    for (int i = 0; i < 4; ++i) { \
      GLD16(pA[i] + (k0), As[buf] + (4 * wv + i) * 1024); \
      GLD16(pB[i] + (k0), Bs[buf] + (4 * wv + i) * 1024); \
    } \
  } while (0)

#define COMPUTE1(buf) do { \
    const int t = lane >> 4; \
    i32x8 af[4], bfr[4]; \
    _Pragma("unroll") \
    for (int m16 = 0; m16 < 4; ++m16) { \
      int row = wr + m16 * 16 + (lane & 15); \
      int x = row & 7; \
      const char* rb = As[buf] + row * 128; \
      int4 lo = *(const int4*)(rb + ((2 * t) ^ x) * 16); \
      int4 hi = *(const int4*)(rb + ((2 * t + 1) ^ x) * 16); \
      af[m16] = (i32x8){lo.x, lo.y, lo.z, lo.w, hi.x, hi.y, hi.z, hi.w}; \
    } \
    _Pragma("unroll") \
    for (int n16 = 0; n16 < 4; ++n16) { \
      int row = wc + n16 * 16 + (lane & 15); \
      int x = row & 7; \
      const char* rb = Bs[buf] + row * 128; \
      int4 lo = *(const int4*)(rb + ((2 * t) ^ x) * 16); \
      int4 hi = *(const int4*)(rb + ((2 * t + 1) ^ x) * 16); \
      bfr[n16] = (i32x8){lo.x, lo.y, lo.z, lo.w, hi.x, hi.y, hi.z, hi.w}; \
    } \
    _Pragma("unroll") \
    for (int m16 = 0; m16 < 4; ++m16) \
      _Pragma("unroll") \
      for (int n16 = 0; n16 < 4; ++n16) \
        acc[m16][n16] = __builtin_amdgcn_mfma_scale_f32_16x16x128_f8f6f4( \
            bfr[n16], af[m16], acc[m16][n16], 0, 0, \
            0, 0x7F7F7F7F, 0, 0x7F7F7F7F); \
  } while (0)

  STAGE1(0, 0);
  __syncthreads();
#pragma unroll
  for (int kt = 0; kt < 5; ++kt) {
    const int cur = kt & 1;
    STAGE1(cur ^ 1, (kt + 1) * 128);
    COMPUTE1(cur);
    __syncthreads();
  }
  COMPUTE1(1);

#pragma unroll
  for (int n16 = 0; n16 < 4; ++n16) {
    int cbase = wc + n16 * 16 + ((lane >> 4) * 4);
    bool isq = (cbase < 64);
    int d = cbase & 63;
    float4 bv = *(const float4*)&bias[h * 128 + cbase];
#pragma unroll
    for (int m16 = 0; m16 < 4; ++m16) {
      int sg = m0 + wr + m16 * 16 + (lane & 15);
      int sl = sg & 511, b = sg >> 9;
      f32x4 v = acc[m16][n16];
      float q0 = v[0] + bv.x, q1 = v[1] + bv.y, q2 = v[2] + bv.z, q3 = v[3] + bv.w;
      float r0 = q0, r1 = q1, r2 = q2, r3 = q3;
      if (isq) {
        float4 C = *(const float4*)&ropeC[sl * 64 + d];
        float4 S = *(const float4*)&ropeS[sl * 64 + d];
        r0 = q0 * C.x - q1 * S.x;
        r1 = q1 * C.y + q0 * S.y;
        r2 = q2 * C.z - q3 * S.z;
        r3 = q3 * C.w + q2 * S.w;
      }
      ushort4 o;
      o.x = f2bf_bits(r0); o.y = f2bf_bits(r1);
      o.z = f2bf_bits(r2); o.w = f2bf_bits(r3);
      size_t off = (((size_t)(b * 24 + h) * 512) + sl) * 64 + d;
      *(ushort4*)((isq ? Qo : Ko) + off) = o;
    }
  }
#undef STAGE1
#undef COMPUTE1
}

// ---------------- GEMM2 v5: 768 blocks x 256 thr, 256x256 quadrant ----------------
// K-only LDS (32KB, XOR-swizzled) -> 4 blocks/CU; Q fragments direct from
// global (read once, L2-resident); lean mask/causal epilogue; REGULAR f32x4 stores.
__global__ __launch_bounds__(256, 4) void gemm2_kernel(
    const bf16_t* __restrict__ Q, const bf16_t* __restrict__ K,
    const float* __restrict__ mask, float* __restrict__ out) {
  __shared__ __align__(16) bf16_t Ks[256 * 64];
  const int tid = threadIdx.x;
  const int lane = tid & 63;
  const int wv = tid >> 6;          // 0..3

  // 768 blocks: XCD gets 96 consecutive logical ids = 24 heads x 4 quads
  const int swz = (blockIdx.x & 7) * 96 + (blockIdx.x >> 3);
  const int bh = swz >> 2;
  const int quad = swz & 3;
  const int m0 = (quad >> 1) * 256;   // row quadrant
  const int n0 = (quad & 1) * 256;    // col quadrant
  const int b = bh / 24;
  const size_t base = (size_t)bh * 512 * 64;

  // stage K rows n0..n0+255 (256 rows x 128B, 8 GLD16/thread)
#pragma unroll
  for (int i = 0; i < 8; ++i) {
    int row = i * 32 + (tid >> 3);
    int slot = tid & 7;
    int srcslot = slot ^ (row & 7);
    GLD16(K + base + (size_t)(n0 + row) * 64 + srcslot * 8, Ks + row * 64 + slot * 8);
  }

  // Q fragments direct from global (this wave's 64 rows; no LDS round-trip)
  const bf16_t* Qg = Q + base;
  bf16x8 af[4][2];
#pragma unroll
  for (int m16 = 0; m16 < 4; ++m16) {
    int row = m0 + wv * 64 + m16 * 16 + (lane & 15);
#pragma unroll
    for (int kk = 0; kk < 2; ++kk) {
      int sl = (lane >> 4) + kk * 4;
      af[m16][kk] = *(const bf16x8*)(Qg + (size_t)row * 64 + sl * 8);
    }
  }

  const float* mb = mask + (size_t)b * 512;
  float* ob = out + (size_t)bh * 512 * 512;

  float mr[4], rb[4];
#pragma unroll
  for (int m16 = 0; m16 < 4; ++m16) {
    mr[m16] = mb[m0 + wv * 64 + m16 * 16 + (lane & 15)];
    rb[m16] = -NEG_INF * (1.0f - mr[m16]);
  }
  float czk[4];
#pragma unroll
  for (int j = 0; j < 4; ++j)
    czk[j] = ((lane & 15) > ((lane >> 4) * 4 + j)) ? K1_8TH : 0.0f;

  __syncthreads();   // K staged (vmcnt drained by barrier semantics)

#pragma unroll 1
  for (int nc = 0; nc < 4; ++nc) {      // 4 column chunks of 64
    f32x4 acc[4][4];
#pragma unroll
    for (int i = 0; i < 4; ++i)
#pragma unroll
      for (int j = 0; j < 4; ++j) acc[i][j] = (f32x4){0.f, 0.f, 0.f, 0.f};

    bf16x8 bfr[4][2];
#pragma unroll
    for (int n16 = 0; n16 < 4; ++n16) {
      int row = nc * 64 + n16 * 16 + (lane & 15);
      int x = row & 7;
#pragma unroll
      for (int kk = 0; kk < 2; ++kk) {
        int sl = ((lane >> 4) + kk * 4) ^ x;
        bfr[n16][kk] = *(const bf16x8*)(Ks + row * 64 + sl * 8);
      }
    }
#pragma unroll
    for (int kk = 0; kk < 2; ++kk)
#pragma unroll
      for (int m16 = 0; m16 < 4; ++m16)
#pragma unroll
        for (int n16 = 0; n16 < 4; ++n16)
          acc[m16][n16] = __builtin_amdgcn_mfma_f32_16x16x32_bf16(
              bfr[n16][kk], af[m16][kk], acc[m16][n16], 0, 0, 0);

    float4 CM[4], colC[4];
#pragma unroll
    for (int n16 = 0; n16 < 4; ++n16) {
      int nb = n0 + nc * 64 + n16 * 16 + ((lane >> 4) * 4);
      float4 mc4 = *(const float4*)&mb[nb];
      CM[n16].x = mc4.x * 0.125f; CM[n16].y = mc4.y * 0.125f;
      CM[n16].z = mc4.z * 0.125f; CM[n16].w = mc4.w * 0.125f;
      colC[n16].x = K1_8TH * mc4.x - K1_8TH;
      colC[n16].y = K1_8TH * mc4.y - K1_8TH;
      colC[n16].z = K1_8TH * mc4.z - K1_8TH;
      colC[n16].w = K1_8TH * mc4.w - K1_8TH;
    }

#pragma unroll
    for (int m16 = 0; m16 < 4; ++m16) {
      int mgl = wv * 64 + m16 * 16 + (lane & 15);
      int t0 = m0 + wv * 64 + m16 * 16;
      float* rowp = ob + (size_t)(m0 + mgl) * 512;
#pragma unroll
      for (int n16 = 0; n16 < 4; ++n16) {
        int c0 = n0 + nc * 64 + n16 * 16;
        int nbl = nc * 64 + n16 * 16 + ((lane >> 4) * 4);
        f32x4 v = acc[m16][n16];
        float a0 = mr[m16] * CM[n16].x, a1 = mr[m16] * CM[n16].y;
        float a2 = mr[m16] * CM[n16].z, a3 = mr[m16] * CM[n16].w;
        float d0 = rb[m16] * CM[n16].x + colC[n16].x;
        float d1 = rb[m16] * CM[n16].y + colC[n16].y;
        float d2 = rb[m16] * CM[n16].z + colC[n16].z;
        float d3 = rb[m16] * CM[n16].w + colC[n16].w;
        if (t0 > c0) {          // fully causal tile
          d0 -= K1_8TH; d1 -= K1_8TH; d2 -= K1_8TH; d3 -= K1_8TH;
        } else if (t0 == c0) {  // diagonal tile: lane-constant mask
          d0 -= czk[0]; d1 -= czk[1]; d2 -= czk[2]; d3 -= czk[3];
        }
        f32x4 st;
        st[0] = v[0] * a0 + d0;
        st[1] = v[1] * a1 + d1;
        st[2] = v[2] * a2 + d2;
        st[3] = v[3] * a3 + d3;
        *(f32x4*)(rowp + n0 + nbl) = st;   // regular store (nt was -48us)
      }
    }
  }
}

extern "C" void kernel_launch(void* const* d_in, const int* in_sizes, int n_in,
                              void* d_out, int out_size, void* d_ws, size_t ws_size,
                              hipStream_t stream) {
  const float* inputs = (const float*)d_in[0];
  const float* mask = (const float*)d_in[1];
  const float* W = (const float*)d_in[2];
  const float* bias = (const float*)d_in[3];
  float* out = (float*)d_out;
  char* ws = (char*)d_ws;

  char* A8 = ws + WS_A8;
  char* Wt8 = ws + WS_WT8;
  unsigned short* Qb = (unsigned short*)(ws + WS_Q);
  unsigned short* Kb = (unsigned short*)(ws + WS_K);
  float* ropeC = (float*)(ws + WS_RC);
  float* ropeS = (float*)(ws + WS_RS);

  prep_kernel<<<3200, 256, 0, stream>>>((const float4*)inputs, (int4*)A8, W, Wt8,
                                        ropeC, ropeS);
  gemm1_kernel<<<768, 256, 0, stream>>>(A8, Wt8, bias, ropeC, ropeS, Qb, Kb);
  gemm2_kernel<<<768, 256, 0, stream>>>((const bf16_t*)Qb, (const bf16_t*)Kb,
                                        mask, out);
}

// Round 13
// 79.240 us; speedup vs baseline: 1.7638x; 1.7638x over previous
//
#include <hip/hip_runtime.h>
#include <hip/hip_bf16.h>

// GlobalPointer logits: x = inputs@W+b -> split q/k per head -> RoPE(q) ->
// logits[b,h,m,n] = <q[b,m,h,:], k[b,n,h,:]> with mask+causal, /8.
// B=8 S=512 DIM=768 H=24 D=64. Output [8][24][512][512] f32.
// GEMM1 in MX-fp8 (e4m3, scale=1.0), swapped-operand MFMA.
// GEMM2 v3 (known-good R7): 768 blocks x 256 thr, one 256x256 quadrant per
// block, Q+K staged in 64KB LDS (2 blocks/CU, no VGPR cap), XCD-swizzled,
// lean epilogue with tile-uniform causal classes. v4/v5 variants (Q-direct,
// 4 blocks/CU cap, nt stores) all regressed -- reverted.

typedef __bf16 bf16_t;
typedef __attribute__((ext_vector_type(8))) __bf16 bf16x8;
typedef __attribute__((ext_vector_type(4))) float f32x4;
typedef __attribute__((ext_vector_type(8))) int i32x8;

#define NEG_INF 1000000000000.0f
#define K1_8TH  125000000000.0f   // NEG_INF/8

// ws layout (bytes)
#define WS_A8   0                  // inputs fp8 [4096][768]    : 3,145,728
#define WS_WT8  3145728            // W^T fp8 [3072][768]       : 2,359,296
#define WS_Q    5505024            // Q bf16 [8][24][512][64]   : 12,582,912
#define WS_K    18087936           // K bf16 [8][24][512][64]   : 12,582,912
#define WS_RC   30670848           // ropeC f32 [512][64]       : 131,072
#define WS_RS   30801920           // ropeS f32 [512][64]       : 131,072

__device__ __forceinline__ unsigned short f2bf_bits(float x) {
  union { float f; unsigned u; } v; v.f = x;
  unsigned r = v.u + 0x7FFFu + ((v.u >> 16) & 1u);
  return (unsigned short)(r >> 16);
}

__device__ __forceinline__ int pack4_fp8(float a, float b, float c, float d) {
  int w = __builtin_amdgcn_cvt_pk_fp8_f32(a, b, 0, false);
  w = __builtin_amdgcn_cvt_pk_fp8_f32(c, d, w, true);
  return w;
}

#define GLD16(g, l) __builtin_amdgcn_global_load_lds( \
    (const __attribute__((address_space(1))) void*)(g), \
    (__attribute__((address_space(3))) void*)(l), 16, 0, 0)

// ---------------- fused prep ----------------
__global__ void prep_kernel(const float4* __restrict__ in, int4* __restrict__ outA,
                            const float* __restrict__ W, char* __restrict__ Wt8,
                            float* __restrict__ ropeC, float* __restrict__ ropeS) {
  __shared__ float s[32][33];
  if (blockIdx.x < 768) {
    int g = blockIdx.x * 256 + threadIdx.x;
    float4 v0 = in[g * 4 + 0];
    float4 v1 = in[g * 4 + 1];
    float4 v2 = in[g * 4 + 2];
    float4 v3 = in[g * 4 + 3];
    int4 o;
    o.x = pack4_fp8(v0.x, v0.y, v0.z, v0.w);
    o.y = pack4_fp8(v1.x, v1.y, v1.z, v1.w);
    o.z = pack4_fp8(v2.x, v2.y, v2.z, v2.w);
    o.w = pack4_fp8(v3.x, v3.y, v3.z, v3.w);
    outA[g] = o;
  } else if (blockIdx.x < 3072) {
    int bid = blockIdx.x - 768;
    int n0 = (bid % 96) * 32, k0 = (bid / 96) * 32;
    int tx = threadIdx.x & 31, ty = threadIdx.x >> 5;
#pragma unroll
    for (int r = 0; r < 4; ++r) {
      int k = k0 + ty + r * 8;
      s[ty + r * 8][tx] = W[(size_t)k * 3072 + n0 + tx];
    }
    __syncthreads();
    int kx = threadIdx.x & 7, tn = threadIdx.x >> 3;
    int w = pack4_fp8(s[4 * kx + 0][tn], s[4 * kx + 1][tn],
                      s[4 * kx + 2][tn], s[4 * kx + 3][tn]);
    *(int*)(Wt8 + (size_t)(n0 + tn) * 768 + k0 + 4 * kx) = w;
  } else {
    int g = (blockIdx.x - 3072) * 256 + threadIdx.x;
    int sp = g >> 6, c = g & 63;
    float inv = exp2f((float)(c >> 1) * -0.4152410118609203f);
    float ang = (float)sp * inv;
    float sn, cs;
    sincosf(ang, &sn, &cs);
    ropeC[g] = cs;
    ropeS[g] = sn;
  }
}

// ---------------- GEMM1 (MX-fp8): X = A*Wt^T + b, RoPE(q), split ----------------
__global__ __launch_bounds__(256) void gemm1_kernel(
    const char* __restrict__ A8, const char* __restrict__ Bt8,
    const float* __restrict__ bias,
    const float* __restrict__ ropeC, const float* __restrict__ ropeS,
    unsigned short* __restrict__ Qo, unsigned short* __restrict__ Ko) {
  __shared__ __align__(16) char As[2][128 * 128];
  __shared__ __align__(16) char Bs[2][128 * 128];
  const int tid = threadIdx.x;
  const int lane = tid & 63;
  const int wv = tid >> 6;
  const int wr = (wv >> 1) * 64;
  const int wc = (wv & 1) * 64;

  const int bid = blockIdx.x;
  const int swz = (bid & 7) * 96 + (bid >> 3);
  const int h = swz % 24;
  const int m0 = (swz / 24) * 128;
  const int n0 = h * 128;

  f32x4 acc[4][4];
#pragma unroll
  for (int i = 0; i < 4; ++i)
#pragma unroll
    for (int j = 0; j < 4; ++j) acc[i][j] = (f32x4){0.f, 0.f, 0.f, 0.f};

  const char* pA[4];
  const char* pB[4];
#pragma unroll
  for (int i = 0; i < 4; ++i) {
    int c = 4 * wv + i;
    int row = c * 8 + (lane >> 3);
    int srcslot = (lane & 7) ^ (row & 7);
    pA[i] = A8 + (size_t)(m0 + row) * 768 + srcslot * 16;
    pB[i] = Bt8 + (size_t)(n0 + row) * 768 + srcslot * 16;
  }

#define STAGE1(buf, k0) do { \
    _Pragma("unroll") \
    for (int i = 0; i < 4; ++i) { \
      GLD16(pA[i] + (k0), As[buf] + (4 * wv + i) * 1024); \
      GLD16(pB[i] + (k0), Bs[buf] + (4 * wv + i) * 1024); \
    } \
  } while (0)

#define COMPUTE1(buf) do { \
    const int t = lane >> 4; \
    i32x8 af[4], bfr[4]; \
    _Pragma("unroll") \
    for (int m16 = 0; m16 < 4; ++m16) { \
      int row = wr + m16 * 16 + (lane & 15); \
      int x = row & 7; \
      const char* rb = As[buf] + row * 128; \
      int4 lo = *(const int4*)(rb + ((2 * t) ^ x) * 16); \
      int4 hi = *(const int4*)(rb + ((2 * t + 1) ^ x) * 16); \
      af[m16] = (i32x8){lo.x, lo.y, lo.z, lo.w, hi.x, hi.y, hi.z, hi.w}; \
    } \
    _Pragma("unroll") \
    for (int n16 = 0; n16 < 4; ++n16) { \
      int row = wc + n16 * 16 + (lane & 15); \
      int x = row & 7; \
      const char* rb = Bs[buf] + row * 128; \
      int4 lo = *(const int4*)(rb + ((2 * t) ^ x) * 16); \
      int4 hi = *(const int4*)(rb + ((2 * t + 1) ^ x) * 16); \
      bfr[n16] = (i32x8){lo.x, lo.y, lo.z, lo.w, hi.x, hi.y, hi.z, hi.w}; \
    } \
    _Pragma("unroll") \
    for (int m16 = 0; m16 < 4; ++m16) \
      _Pragma("unroll") \
      for (int n16 = 0; n16 < 4; ++n16) \
        acc[m16][n16] = __builtin_amdgcn_mfma_scale_f32_16x16x128_f8f6f4( \
            bfr[n16], af[m16], acc[m16][n16], 0, 0, \
            0, 0x7F7F7F7F, 0, 0x7F7F7F7F); \
  } while (0)

  STAGE1(0, 0);
  __syncthreads();
#pragma unroll
  for (int kt = 0; kt < 5; ++kt) {
    const int cur = kt & 1;
    STAGE1(cur ^ 1, (kt + 1) * 128);
    COMPUTE1(cur);
    __syncthreads();
  }
  COMPUTE1(1);

#pragma unroll
  for (int n16 = 0; n16 < 4; ++n16) {
    int cbase = wc + n16 * 16 + ((lane >> 4) * 4);
    bool isq = (cbase < 64);
    int d = cbase & 63;
    float4 bv = *(const float4*)&bias[h * 128 + cbase];
#pragma unroll
    for (int m16 = 0; m16 < 4; ++m16) {
      int sg = m0 + wr + m16 * 16 + (lane & 15);
      int sl = sg & 511, b = sg >> 9;
      f32x4 v = acc[m16][n16];
      float q0 = v[0] + bv.x, q1 = v[1] + bv.y, q2 = v[2] + bv.z, q3 = v[3] + bv.w;
      float r0 = q0, r1 = q1, r2 = q2, r3 = q3;
      if (isq) {
        float4 C = *(const float4*)&ropeC[sl * 64 + d];
        float4 S = *(const float4*)&ropeS[sl * 64 + d];
        r0 = q0 * C.x - q1 * S.x;
        r1 = q1 * C.y + q0 * S.y;
        r2 = q2 * C.z - q3 * S.z;
        r3 = q3 * C.w + q2 * S.w;
      }
      ushort4 o;
      o.x = f2bf_bits(r0); o.y = f2bf_bits(r1);
      o.z = f2bf_bits(r2); o.w = f2bf_bits(r3);
      size_t off = (((size_t)(b * 24 + h) * 512) + sl) * 64 + d;
      *(ushort4*)((isq ? Qo : Ko) + off) = o;
    }
  }
#undef STAGE1
#undef COMPUTE1
}

// ---------------- GEMM2 v3: 768 blocks x 256 thr, 256x256 quadrant ----------------
// Block -> (bh, quad): XCD-swizzled so one head's 4 quadrants land on one XCD.
// Q rows [m0,m0+256) + K rows [n0,n0+256) staged once (64KB, XOR-swizzled).
// Wave w owns 64 rows; 4 column chunks of {8 ds_read + 32 MFMA + lean epilogue}.
__global__ __launch_bounds__(256, 2) void gemm2_kernel(
    const bf16_t* __restrict__ Q, const bf16_t* __restrict__ K,
    const float* __restrict__ mask, float* __restrict__ out) {
  __shared__ __align__(16) bf16_t Qs[256 * 64];
  __shared__ __align__(16) bf16_t Ks[256 * 64];
  const int tid = threadIdx.x;
  const int lane = tid & 63;
  const int wv = tid >> 6;          // 0..3

  // 768 blocks: XCD gets 96 consecutive logical ids = 24 heads x 4 quads
  const int swz = (blockIdx.x & 7) * 96 + (blockIdx.x >> 3);
  const int bh = swz >> 2;
  const int quad = swz & 3;
  const int m0 = (quad >> 1) * 256;   // row quadrant
  const int n0 = (quad & 1) * 256;    // col quadrant
  const int b = bh / 24;
  const size_t base = (size_t)bh * 512 * 64;

  // stage Q rows m0.., K rows n0..: 256 rows x 128B each
#pragma unroll
  for (int i = 0; i < 8; ++i) {
    int row = i * 32 + (tid >> 3);
    int slot = tid & 7;
    int srcslot = slot ^ (row & 7);
    GLD16(Q + base + (size_t)(m0 + row) * 64 + srcslot * 8, Qs + row * 64 + slot * 8);
    GLD16(K + base + (size_t)(n0 + row) * 64 + srcslot * 8, Ks + row * 64 + slot * 8);
  }
  __syncthreads();

  // hoist Q fragments for this wave's 64 rows
  bf16x8 af[4][2];
#pragma unroll
  for (int m16 = 0; m16 < 4; ++m16) {
    int row = wv * 64 + m16 * 16 + (lane & 15);
    int x = row & 7;
#pragma unroll
    for (int kk = 0; kk < 2; ++kk) {
      int sl = ((lane >> 4) + kk * 4) ^ x;
      af[m16][kk] = *(const bf16x8*)(Qs + row * 64 + sl * 8);
    }
  }

  const float* mb = mask + (size_t)b * 512;
  float* ob = out + (size_t)bh * 512 * 512;

  // per-wave row-mask terms
  float mr[4], rb[4];
#pragma unroll
  for (int m16 = 0; m16 < 4; ++m16) {
    mr[m16] = mb[m0 + wv * 64 + m16 * 16 + (lane & 15)];
    rb[m16] = -NEG_INF * (1.0f - mr[m16]);
  }
  // diagonal-tile causal term (lane-constant)
  float czk[4];
#pragma unroll
  for (int j = 0; j < 4; ++j)
    czk[j] = ((lane & 15) > ((lane >> 4) * 4 + j)) ? K1_8TH : 0.0f;

#pragma unroll 1
  for (int nc = 0; nc < 4; ++nc) {      // 4 column chunks of 64
    f32x4 acc[4][4];
#pragma unroll
    for (int i = 0; i < 4; ++i)
#pragma unroll
      for (int j = 0; j < 4; ++j) acc[i][j] = (f32x4){0.f, 0.f, 0.f, 0.f};

    bf16x8 bfr[4][2];
#pragma unroll
    for (int n16 = 0; n16 < 4; ++n16) {
      int row = nc * 64 + n16 * 16 + (lane & 15);
      int x = row & 7;
#pragma unroll
      for (int kk = 0; kk < 2; ++kk) {
        int sl = ((lane >> 4) + kk * 4) ^ x;
        bfr[n16][kk] = *(const bf16x8*)(Ks + row * 64 + sl * 8);
      }
    }
#pragma unroll
    for (int kk = 0; kk < 2; ++kk)
#pragma unroll
      for (int m16 = 0; m16 < 4; ++m16)
#pragma unroll
        for (int n16 = 0; n16 < 4; ++n16)
          acc[m16][n16] = __builtin_amdgcn_mfma_f32_16x16x32_bf16(
              bfr[n16][kk], af[m16][kk], acc[m16][n16], 0, 0, 0);

    // per-chunk column terms: CM = mc/8, colC = K1*mc - K1
    float4 CM[4], colC[4];
#pragma unroll
    for (int n16 = 0; n16 < 4; ++n16) {
      int nb = n0 + nc * 64 + n16 * 16 + ((lane >> 4) * 4);
      float4 mc4 = *(const float4*)&mb[nb];
      CM[n16].x = mc4.x * 0.125f; CM[n16].y = mc4.y * 0.125f;
      CM[n16].z = mc4.z * 0.125f; CM[n16].w = mc4.w * 0.125f;
      colC[n16].x = K1_8TH * mc4.x - K1_8TH;
      colC[n16].y = K1_8TH * mc4.y - K1_8TH;
      colC[n16].z = K1_8TH * mc4.z - K1_8TH;
      colC[n16].w = K1_8TH * mc4.w - K1_8TH;
    }

#pragma unroll
    for (int m16 = 0; m16 < 4; ++m16) {
      int mgl = wv * 64 + m16 * 16 + (lane & 15);      // local row
      int t0 = m0 + wv * 64 + m16 * 16;                 // tile row base (global)
      float* rowp = ob + (size_t)(m0 + mgl) * 512;
#pragma unroll
      for (int n16 = 0; n16 < 4; ++n16) {
        int c0 = n0 + nc * 64 + n16 * 16;               // tile col base (global)
        int nbl = nc * 64 + n16 * 16 + ((lane >> 4) * 4);  // local col
        f32x4 v = acc[m16][n16];
        float a0 = mr[m16] * CM[n16].x, a1 = mr[m16] * CM[n16].y;
        float a2 = mr[m16] * CM[n16].z, a3 = mr[m16] * CM[n16].w;
        float d0 = rb[m16] * CM[n16].x + colC[n16].x;
        float d1 = rb[m16] * CM[n16].y + colC[n16].y;
        float d2 = rb[m16] * CM[n16].z + colC[n16].z;
        float d3 = rb[m16] * CM[n16].w + colC[n16].w;
        if (t0 > c0) {          // fully causal tile
          d0 -= K1_8TH; d1 -= K1_8TH; d2 -= K1_8TH; d3 -= K1_8TH;
        } else if (t0 == c0) {  // diagonal tile: lane-constant mask
          d0 -= czk[0]; d1 -= czk[1]; d2 -= czk[2]; d3 -= czk[3];
        }                       // t0 < c0: no causal
        float4 st;
        st.x = v[0] * a0 + d0;
        st.y = v[1] * a1 + d1;
        st.z = v[2] * a2 + d2;
        st.w = v[3] * a3 + d3;
        *(float4*)(rowp + n0 + nbl) = st;
      }
    }
  }
}

extern "C" void kernel_launch(void* const* d_in, const int* in_sizes, int n_in,
                              void* d_out, int out_size, void* d_ws, size_t ws_size,
                              hipStream_t stream) {
  const float* inputs = (const float*)d_in[0];
  const float* mask = (const float*)d_in[1];
  const float* W = (const float*)d_in[2];
  const float* bias = (const float*)d_in[3];
  float* out = (float*)d_out;
  char* ws = (char*)d_ws;

  char* A8 = ws + WS_A8;
  char* Wt8 = ws + WS_WT8;
  unsigned short* Qb = (unsigned short*)(ws + WS_Q);
  unsigned short* Kb = (unsigned short*)(ws + WS_K);
  float* ropeC = (float*)(ws + WS_RC);
  float* ropeS = (float*)(ws + WS_RS);

  prep_kernel<<<3200, 256, 0, stream>>>((const float4*)inputs, (int4*)A8, W, Wt8,
                                        ropeC, ropeS);
  gemm1_kernel<<<768, 256, 0, stream>>>(A8, Wt8, bias, ropeC, ropeS, Qb, Kb);
  gemm2_kernel<<<768, 256, 0, stream>>>((const bf16_t*)Qb, (const bf16_t*)Kb,
                                        mask, out);
}